// Round 12
// baseline (239.785 us; speedup 1.0000x reference)
//
#include <hip/hip_runtime.h>
#include <cstdint>

#define F_IN   8
#define HID    64
#define F_OUTD 8
#define RDIM   256
#define CDIM   4096
#define NSETS  3
#define NIND   4096
#define MDIM   4096
#define MAXL   64
#define GC     16

using short8 = __attribute__((ext_vector_type(8))) short;
using f32x4  = __attribute__((ext_vector_type(4))) float;

// hardware packed f32->bf16 (RNE), low word = a
__device__ inline unsigned int cvtpk(float a, float b) {
    unsigned int r;
    asm("v_cvt_pk_bf16_f32 %0, %1, %2" : "=v"(r) : "v"(a), "v"(b));
    return r;
}
// packed unsigned 16-bit max (== bf16 max for nonnegative values)
__device__ inline unsigned int pkmaxu(unsigned int a, unsigned int b) {
    unsigned int r;
    asm("v_pk_max_u16 %0, %1, %2" : "=v"(r) : "v"(a), "v"(b));
    return r;
}

// ---------------- input prep: in [F][R][C] f32 -> inT2 [C][R][F] bf16 ----------
__global__ __launch_bounds__(256)
void prep_in(const float* __restrict__ in, unsigned short* __restrict__ out) {
    const int PADH = 264;                       // halfs per c-row (528B)
    __shared__ unsigned short tile[32 * PADH];
    int c0 = blockIdx.x * 32, r0 = blockIdx.y * 32;
    int t = threadIdx.x;
    int tx = t & 31, ty = t >> 5;
#pragma unroll
    for (int f = 0; f < 8; f += 2)
#pragma unroll
        for (int rr = 0; rr < 4; rr++) {
            int r = ty + rr * 8;
            float v0 = in[((size_t)f * RDIM + (r0 + r)) * CDIM + c0 + tx];
            float v1 = in[((size_t)(f + 1) * RDIM + (r0 + r)) * CDIM + c0 + tx];
            *(unsigned int*)&tile[tx * PADH + r * 8 + f] = cvtpk(v0, v1);
        }
    __syncthreads();
    int r = t & 31, cl = t >> 5;
#pragma unroll
    for (int cc = 0; cc < 4; cc++) {
        int c = cc * 8 + cl;
        uint4 v = *(const uint4*)&tile[c * PADH + r * 8];
        *(uint4*)(out + (((size_t)(c0 + c) * RDIM) + (r0 + r)) * 8) = v;
    }
}

// ---------------- setup: inverse perms + mergecnt zero + weight prep ----------
// inv[si][c0]=k s.t. ind_i[s][k][0]==c0; block (0,0) converts weights to bf16.
// w2's columns are permuted by tau so that layer-1's packed relu output
// (D-fragment order) is directly the layer-2 B-fragment:
//   tau(32*hi + 8*q + e) = 32*hi + 16*(e>>2) + 4*q + (e&3)
__global__ void build_inv(const int* __restrict__ ind0, const int* __restrict__ ind1,
                          const int* __restrict__ ind2,
                          const float* __restrict__ w1, const float* __restrict__ w2,
                          int* __restrict__ inv, int* __restrict__ mergecnt,
                          unsigned short* __restrict__ w1bf, unsigned short* __restrict__ w2bf) {
    int k  = blockIdx.x * 256 + threadIdx.x;
    int si = blockIdx.y;
    int s_ = si / 3, i_ = si % 3;
    const int* ind = (i_ == 0 ? ind0 : (i_ == 1 ? ind1 : ind2)) + (size_t)s_ * NIND * 2;
    int c0 = ind[2 * k];
    inv[(size_t)si * NIND + c0] = k;
    if (si == 0) mergecnt[k] = 0;
    if (blockIdx.x == 0 && blockIdx.y == 0) {
        int t = threadIdx.x;
        for (int i = t; i < 64 * 32; i += 256) {
            int j = i >> 5, kk = i & 31;
            w1bf[i] = (kk < 24) ? (unsigned short)(cvtpk(w1[j * 24 + kk], 0.f) & 0xffff) : 0;
        }
        for (int i = t; i < 16 * 64; i += 256) {
            int f = i >> 6, kg = i & 63;
            int hi = kg >> 5, q = (kg >> 3) & 3, e = kg & 7;
            int j = (hi << 5) + ((e >> 2) << 4) + (q << 2) + (e & 3);   // tau
            w2bf[i] = (f < 8) ? (unsigned short)(cvtpk(w2[f * 64 + j], 0.f) & 0xffff) : 0;
        }
    }
}

// ---------------- bucket-invert the scatter into ONE merged list per column --
// mergelist[c][slot] = s*MDIM + m  (the d-tile index contributing to column c)
__global__ void build_buckets(const int* __restrict__ ind0, const int* __restrict__ ind1,
                              const int* __restrict__ ind2, const int* __restrict__ mix,
                              int* __restrict__ mergecnt, int* __restrict__ mergelist) {
    int m  = blockIdx.x * 256 + threadIdx.x;
    int si = blockIdx.y;
    int s_ = si / 3, i_ = si % 3;
    const int* ind = (i_ == 0 ? ind0 : (i_ == 1 ? ind1 : ind2)) + (size_t)s_ * NIND * 2;
    int mi = mix[(size_t)si * MDIM + m];
    int c  = ind[2 * mi + 1];
    int slot = atomicAdd(&mergecnt[c], 1);
    if (slot < MAXL) mergelist[(size_t)c * MAXL + slot] = s_ * MDIM + m;
}

// ---------------- per-(s,m) source-column triple: gtab[sm] = {g0,g1,g2,0} ----
__global__ void build_gtab(const int* __restrict__ ind0, const int* __restrict__ ind1,
                           const int* __restrict__ ind2, const int* __restrict__ mix,
                           const int* __restrict__ inv, int4* __restrict__ gtab) {
    int sm = blockIdx.x * 256 + threadIdx.x;     // 0..12287
    int s  = sm >> 12, m = sm & 4095;
    int g[3];
#pragma unroll
    for (int i = 0; i < 3; i++) {
        int si = s * 3 + i;
        int mi = mix[(size_t)si * MDIM + m];
        int k  = inv[(size_t)si * NIND + mi];
        const int* ind = (i == 0 ? ind0 : (i == 1 ? ind1 : ind2)) + (size_t)s * NIND * 2;
        g[i] = ind[2 * k + 1];
    }
    gtab[sm] = make_int4(g[0], g[1], g[2], 0);
}

// ---------------- fused MLP-recompute + amax gather -> d_out [f][r][c] --------
// grid (CDIM/GC, 16); 1024-thr block = 16 waves. Wave w owns dest column c0+w
// for one 16-row slab. Per list entry: recompute the MLP tile (same fragment
// math as before: tau-permuted w2, bias-in-C) and pkmax into registers.
// Recompute (3x MFMA, pipe only ~15% busy) deletes the 48 MiB dbuf round-trip.
__global__ __launch_bounds__(1024)
void fused_mlp_gather(const unsigned short* __restrict__ inT2,
                      const unsigned short* __restrict__ w1bf,
                      const unsigned short* __restrict__ w2bf,
                      const float* __restrict__ b1, const float* __restrict__ b2,
                      const int* __restrict__ mergecnt, const int* __restrict__ mergelist,
                      const int4* __restrict__ gtab, float* __restrict__ out) {
    __shared__ unsigned int ldsP[4][16][20];   // [fpair][rloc][c] packed bf16 pairs
    __shared__ int glist[GC][MAXL][4];         // per-entry source-column triple
    int t = threadIdx.x;
    int w = t >> 6, lane = t & 63;
    int lo = lane & 15, q = lane >> 4;
    int c0 = blockIdx.x * GC;
    int c  = c0 + w;
    int r16 = blockIdx.y * 16;                 // row-slab base

    // constant fragments (identical math to prior mlp_store)
    short8 A1[4], A2[2];
#pragma unroll
    for (int tt = 0; tt < 4; tt++)
        A1[tt] = *(const short8*)(w1bf + ((16 * tt + lo) << 5) + (q << 3));
#pragma unroll
    for (int kk = 0; kk < 2; kk++)
        A2[kk] = *(const short8*)(w2bf + (lo << 6) + (kk << 5) + (q << 3));
    f32x4 bbv[4];
#pragma unroll
    for (int tt = 0; tt < 4; tt++)
#pragma unroll
        for (int rg = 0; rg < 4; rg++)
            bbv[tt][rg] = b1[16 * tt + 4 * q + rg];
    f32x4 b2f;
#pragma unroll
    for (int rg = 0; rg < 4; rg++) {
        int f = 4 * q + rg;
        b2f[rg] = (f < 8) ? b2[f] : 0.f;
    }
#pragma unroll
    for (int tt = 0; tt < 4; tt++) asm volatile("" : "+v"(A1[tt]));
    asm volatile("" : "+v"(A2[0]), "+v"(A2[1]));

    // prologue: 2 parallel load-rounds fill this wave's entry table
    int n = mergecnt[c];
    n = n < 0 ? 0 : (n > MAXL ? MAXL : n);     // uniform across the wave
    if (lane < n) {
        int sm = mergelist[(size_t)c * MAXL + lane];
        sm = sm < 0 ? 0 : (sm >= NSETS * MDIM ? NSETS * MDIM - 1 : sm);
        *(int4*)&glist[w][lane][0] = gtab[sm];
    }
    __syncthreads();

    const unsigned short* zsrc = w2bf + 512 + lo * 8;   // zero rows (f>=8), 16B ok

    union U { unsigned int u[4]; short8 s; };
    const short8 zero8 = {0, 0, 0, 0, 0, 0, 0, 0};
    uint2 acc; acc.x = 0u; acc.y = 0u;

    short8 Bcur = zero8;
    if (n > 0) {
        int g = glist[w][0][q & 3];
        const unsigned short* p = (q < 3) ? inT2 + ((size_t)g * RDIM + r16 + lo) * 8 : zsrc;
        Bcur = *(const short8*)p;
    }
    for (int e = 0; e < n; e++) {
        short8 Bnext = zero8;
        if (e + 1 < n) {
            int g = glist[w][e + 1][q & 3];
            const unsigned short* p = (q < 3) ? inT2 + ((size_t)g * RDIM + r16 + lo) * 8 : zsrc;
            Bnext = *(const short8*)p;
        }

        f32x4 a0 = __builtin_amdgcn_mfma_f32_16x16x32_bf16(A1[0], Bcur, bbv[0], 0, 0, 0);
        f32x4 a1 = __builtin_amdgcn_mfma_f32_16x16x32_bf16(A1[1], Bcur, bbv[1], 0, 0, 0);
        f32x4 a2 = __builtin_amdgcn_mfma_f32_16x16x32_bf16(A1[2], Bcur, bbv[2], 0, 0, 0);
        f32x4 a3 = __builtin_amdgcn_mfma_f32_16x16x32_bf16(A1[3], Bcur, bbv[3], 0, 0, 0);

        U ba, bb;   // relu(fmaxf, NaN-squashing) + pack = layer-2 B fragment
        ba.u[0] = cvtpk(fmaxf(a0[0], 0.f), fmaxf(a0[1], 0.f));
        ba.u[1] = cvtpk(fmaxf(a0[2], 0.f), fmaxf(a0[3], 0.f));
        ba.u[2] = cvtpk(fmaxf(a1[0], 0.f), fmaxf(a1[1], 0.f));
        ba.u[3] = cvtpk(fmaxf(a1[2], 0.f), fmaxf(a1[3], 0.f));
        bb.u[0] = cvtpk(fmaxf(a2[0], 0.f), fmaxf(a2[1], 0.f));
        bb.u[1] = cvtpk(fmaxf(a2[2], 0.f), fmaxf(a2[3], 0.f));
        bb.u[2] = cvtpk(fmaxf(a3[0], 0.f), fmaxf(a3[1], 0.f));
        bb.u[3] = cvtpk(fmaxf(a3[2], 0.f), fmaxf(a3[3], 0.f));

        f32x4 o = __builtin_amdgcn_mfma_f32_16x16x32_bf16(A2[0], ba.s, b2f, 0, 0, 0);
        o = __builtin_amdgcn_mfma_f32_16x16x32_bf16(A2[1], bb.s, o, 0, 0, 0);

        // clamp>=0 (also squashes NaN), pack, running packed max
        unsigned int ox = cvtpk(fmaxf(o[0], 0.f), fmaxf(o[1], 0.f));
        unsigned int oy = cvtpk(fmaxf(o[2], 0.f), fmaxf(o[3], 0.f));
        acc.x = pkmaxu(acc.x, ox);
        acc.y = pkmaxu(acc.y, oy);

        Bcur = Bnext;
    }

    if (q < 2) {            // lane holds (r = lo, f = 4q+{0..3})
        ldsP[2 * q][lo][w]     = acc.x;   // f 4q+0 (lo half), 4q+1 (hi half)
        ldsP[2 * q + 1][lo][w] = acc.y;   // f 4q+2, 4q+3
    }
    __syncthreads();

    // write out [f][r][c]: 512 threads x one float4 (64B segments per (f,rl))
    if (t < 512) {
        int f = t >> 6, rl = (t >> 2) & 15, cq = t & 3;
        uint4 v = *(const uint4*)&ldsP[f >> 1][rl][cq * 4];
        float4 ov;
        if (f & 1) {
            ov.x = fmaxf(__uint_as_float(v.x & 0xffff0000u), 0.f);
            ov.y = fmaxf(__uint_as_float(v.y & 0xffff0000u), 0.f);
            ov.z = fmaxf(__uint_as_float(v.z & 0xffff0000u), 0.f);
            ov.w = fmaxf(__uint_as_float(v.w & 0xffff0000u), 0.f);
        } else {
            ov.x = fmaxf(__uint_as_float(v.x << 16), 0.f);
            ov.y = fmaxf(__uint_as_float(v.y << 16), 0.f);
            ov.z = fmaxf(__uint_as_float(v.z << 16), 0.f);
            ov.w = fmaxf(__uint_as_float(v.w << 16), 0.f);
        }
        *(float4*)&out[((size_t)f * RDIM + r16 + rl) * CDIM + c0 + cq * 4] = ov;
    }
}

extern "C" void kernel_launch(void* const* d_in, const int* in_sizes, int n_in,
                              void* d_out, int out_size, void* d_ws, size_t ws_size,
                              hipStream_t stream) {
    const float* input = (const float*)d_in[0];
    const float* w1    = (const float*)d_in[1];
    const float* b1    = (const float*)d_in[2];
    const float* w2    = (const float*)d_in[3];
    const float* b2    = (const float*)d_in[4];
    const int*   ind0  = (const int*)d_in[5];
    const int*   ind1  = (const int*)d_in[6];
    const int*   ind2  = (const int*)d_in[7];
    const int*   mix   = (const int*)d_in[8];

    const size_t MiB = 1ull << 20;
    char* ws = (char*)d_ws;
    unsigned short* inT2 = (unsigned short*)ws;                    // 16 MiB
    char* tail = ws + 16 * MiB;
    int*  inv       = (int*)tail;                                  // 144 KiB
    int*  mergecnt  = (int*)(tail + 147456);                       // 16 KiB
    int*  mergelist = (int*)(tail + 147456 + 16384);               // 1 MiB
    int4* gtab      = (int4*)(tail + 147456 + 16384 + (size_t)CDIM * MAXL * 4);  // 192 KiB
    unsigned short* w1bf = (unsigned short*)((char*)gtab + (size_t)NSETS * MDIM * 16);
    unsigned short* w2bf = w1bf + 64 * 32;

    prep_in<<<dim3(CDIM / 32, RDIM / 32), 256, 0, stream>>>(input, inT2);
    build_inv<<<dim3(NIND / 256, 9), 256, 0, stream>>>(ind0, ind1, ind2, w1, w2,
                                                       inv, mergecnt, w1bf, w2bf);
    build_buckets<<<dim3(MDIM / 256, 9), 256, 0, stream>>>(ind0, ind1, ind2, mix,
                                                           mergecnt, mergelist);
    build_gtab<<<NSETS * MDIM / 256, 256, 0, stream>>>(ind0, ind1, ind2, mix, inv, gtab);
    fused_mlp_gather<<<dim3(CDIM / GC, 16), 1024, 0, stream>>>(
        inT2, w1bf, w2bf, b1, b2, mergecnt, mergelist, gtab, (float*)d_out);
}

// Round 13
// 86.084 us; speedup vs baseline: 2.7855x; 2.7855x over previous
//
#include <hip/hip_runtime.h>
#include <cstdint>

#define F_IN   8
#define HID    64
#define F_OUTD 8
#define RDIM   256
#define CDIM   4096
#define NSETS  3
#define NIND   4096
#define MDIM   4096
#define MAXL   64
#define GC     16
#define MPW    4

using short8 = __attribute__((ext_vector_type(8))) short;
using f32x4  = __attribute__((ext_vector_type(4))) float;

// hardware packed f32->bf16 (RNE), low word = a
__device__ inline unsigned int cvtpk(float a, float b) {
    unsigned int r;
    asm("v_cvt_pk_bf16_f32 %0, %1, %2" : "=v"(r) : "v"(a), "v"(b));
    return r;
}
// packed unsigned 16-bit max (== bf16 max for nonnegative values)
__device__ inline unsigned int pkmaxu(unsigned int a, unsigned int b) {
    unsigned int r;
    asm("v_pk_max_u16 %0, %1, %2" : "=v"(r) : "v"(a), "v"(b));
    return r;
}

// ---------------- input prep: in [F][R][C] f32 -> inT2 [C][R][F] bf16 ----------
__global__ __launch_bounds__(256)
void prep_in(const float* __restrict__ in, unsigned short* __restrict__ out) {
    const int PADH = 264;                       // halfs per c-row (528B)
    __shared__ unsigned short tile[32 * PADH];
    int c0 = blockIdx.x * 32, r0 = blockIdx.y * 32;
    int t = threadIdx.x;
    int tx = t & 31, ty = t >> 5;
#pragma unroll
    for (int f = 0; f < 8; f += 2)
#pragma unroll
        for (int rr = 0; rr < 4; rr++) {
            int r = ty + rr * 8;
            float v0 = in[((size_t)f * RDIM + (r0 + r)) * CDIM + c0 + tx];
            float v1 = in[((size_t)(f + 1) * RDIM + (r0 + r)) * CDIM + c0 + tx];
            *(unsigned int*)&tile[tx * PADH + r * 8 + f] = cvtpk(v0, v1);
        }
    __syncthreads();
    int r = t & 31, cl = t >> 5;
#pragma unroll
    for (int cc = 0; cc < 4; cc++) {
        int c = cc * 8 + cl;
        uint4 v = *(const uint4*)&tile[c * PADH + r * 8];
        *(uint4*)(out + (((size_t)(c0 + c) * RDIM) + (r0 + r)) * 8) = v;
    }
}

// ---------------- setup: inverse perms + mergecnt zero + weight prep ----------
// inv[si][c0]=k s.t. ind_i[s][k][0]==c0; block (0,0) converts weights to bf16.
// w2's columns are permuted by tau so that layer-1's packed relu output
// (D-fragment order) is directly the layer-2 B-fragment:
//   tau(32*hi + 8*q + e) = 32*hi + 16*(e>>2) + 4*q + (e&3)
__global__ void build_inv(const int* __restrict__ ind0, const int* __restrict__ ind1,
                          const int* __restrict__ ind2,
                          const float* __restrict__ w1, const float* __restrict__ w2,
                          int* __restrict__ inv, int* __restrict__ mergecnt,
                          unsigned short* __restrict__ w1bf, unsigned short* __restrict__ w2bf) {
    int k  = blockIdx.x * 256 + threadIdx.x;
    int si = blockIdx.y;
    int s_ = si / 3, i_ = si % 3;
    const int* ind = (i_ == 0 ? ind0 : (i_ == 1 ? ind1 : ind2)) + (size_t)s_ * NIND * 2;
    int c0 = ind[2 * k];
    inv[(size_t)si * NIND + c0] = k;
    if (si == 0) mergecnt[k] = 0;
    if (blockIdx.x == 0 && blockIdx.y == 0) {
        int t = threadIdx.x;
        for (int i = t; i < 64 * 32; i += 256) {
            int j = i >> 5, kk = i & 31;
            w1bf[i] = (kk < 24) ? (unsigned short)(cvtpk(w1[j * 24 + kk], 0.f) & 0xffff) : 0;
        }
        for (int i = t; i < 16 * 64; i += 256) {
            int f = i >> 6, kg = i & 63;
            int hi = kg >> 5, q = (kg >> 3) & 3, e = kg & 7;
            int j = (hi << 5) + ((e >> 2) << 4) + (q << 2) + (e & 3);   // tau
            w2bf[i] = (f < 8) ? (unsigned short)(cvtpk(w2[f * 64 + j], 0.f) & 0xffff) : 0;
        }
    }
}

// ---------------- bucket-invert the scatter into ONE merged list per column --
// mergelist[c][slot] = s*MDIM + m  (the d-tile index contributing to column c)
__global__ void build_buckets(const int* __restrict__ ind0, const int* __restrict__ ind1,
                              const int* __restrict__ ind2, const int* __restrict__ mix,
                              int* __restrict__ mergecnt, int* __restrict__ mergelist) {
    int m  = blockIdx.x * 256 + threadIdx.x;
    int si = blockIdx.y;
    int s_ = si / 3, i_ = si % 3;
    const int* ind = (i_ == 0 ? ind0 : (i_ == 1 ? ind1 : ind2)) + (size_t)s_ * NIND * 2;
    int mi = mix[(size_t)si * MDIM + m];
    int c  = ind[2 * mi + 1];
    int slot = atomicAdd(&mergecnt[c], 1);
    if (slot < MAXL) mergelist[(size_t)c * MAXL + slot] = s_ * MDIM + m;
}

// ---------------- MFMA MLP -> dense d[s*M+m][r][f] bf16 (clamped at 0) -----
// One wave per (s, half-of-r, group of MPW m). Fully in-register; w2 columns
// pre-permuted by tau so layer-1's packed relu output IS the layer-2 B frag.
// Loop-invariant fragments pinned via opaque empty asm.
__global__ __launch_bounds__(256, 2)
void mlp_store(const unsigned short* __restrict__ inT2,
               const unsigned short* __restrict__ w1bf,
               const unsigned short* __restrict__ w2bf,
               const float* __restrict__ b1, const float* __restrict__ b2,
               const int* __restrict__ ind0, const int* __restrict__ ind1,
               const int* __restrict__ ind2, const int* __restrict__ mix,
               const int* __restrict__ inv,
               unsigned short* __restrict__ dbuf) {
    int t    = threadIdx.x;
    int wave = t >> 6, lane = t & 63;
    int lo = lane & 15, q = lane >> 4;

    int wid  = blockIdx.x * 4 + wave;    // 0..6143
    int mgrp = wid & 1023;
    int half = (wid >> 10) & 1;
    int s_   = wid >> 11;
    int m0   = mgrp * MPW;

    short8 A1[4], A2[2];
#pragma unroll
    for (int tt = 0; tt < 4; tt++)
        A1[tt] = *(const short8*)(w1bf + ((16 * tt + lo) << 5) + (q << 3));
#pragma unroll
    for (int kk = 0; kk < 2; kk++)
        A2[kk] = *(const short8*)(w2bf + (lo << 6) + (kk << 5) + (q << 3));

    // biases as MFMA C-operand fragments
    f32x4 bbv[4];
#pragma unroll
    for (int tt = 0; tt < 4; tt++)
#pragma unroll
        for (int rg = 0; rg < 4; rg++)
            bbv[tt][rg] = b1[16 * tt + 4 * q + rg];
    f32x4 b2f;
#pragma unroll
    for (int rg = 0; rg < 4; rg++) {
        int f = 4 * q + rg;
        b2f[rg] = (f < 8) ? b2[f] : 0.f;
    }

    // pin invariants: opaque asm kills rematerialization -> held in VGPRs
#pragma unroll
    for (int tt = 0; tt < 4; tt++) asm volatile("" : "+v"(A1[tt]));
    asm volatile("" : "+v"(A2[0]), "+v"(A2[1]));
#pragma unroll
    for (int tt = 0; tt < 4; tt++) asm volatile("" : "+v"(bbv[tt]));
    asm volatile("" : "+v"(b2f));

    // batched index chase: 3 rounds of MPW independent loads
    int gq[MPW] = {0, 0, 0, 0};
    if (q < 3) {
        int si = s_ * 3 + q;
        const int* indq = (q == 0 ? ind0 : (q == 1 ? ind1 : ind2)) + (size_t)s_ * NIND * 2;
        int mi[MPW], kk[MPW];
#pragma unroll
        for (int u = 0; u < MPW; u++) mi[u] = mix[(size_t)si * MDIM + m0 + u];
#pragma unroll
        for (int u = 0; u < MPW; u++) kk[u] = inv[(size_t)si * NIND + mi[u]];
#pragma unroll
        for (int u = 0; u < MPW; u++) gq[u] = indq[2 * kk[u] + 1];
    }
    const unsigned short* srcs[MPW];
#pragma unroll
    for (int u = 0; u < MPW; u++)
        srcs[u] = inT2 + ((size_t)gq[u] * RDIM + half * 128 + lo) * 8;

    unsigned short* dst = dbuf + (size_t)(s_ * MDIM + m0) * 2048 + half * 1024 + lo * 8 + q * 4;

    union U { unsigned int u[4]; short8 s; };
    const short8 zero8 = {0, 0, 0, 0, 0, 0, 0, 0};

    short8 Bcur = zero8;
    if (q < 3) Bcur = *(const short8*)srcs[0];
#pragma unroll
    for (int it = 0; it < MPW * 8; it++) {
        const int u = it >> 3, j = it & 7;
        short8 Bnext = Bcur;
        if (it < MPW * 8 - 1 && q < 3)
            Bnext = *(const short8*)(srcs[(it + 1) >> 3] + ((it + 1) & 7) * 128);

        f32x4 a0 = __builtin_amdgcn_mfma_f32_16x16x32_bf16(A1[0], Bcur, bbv[0], 0, 0, 0);
        f32x4 a1 = __builtin_amdgcn_mfma_f32_16x16x32_bf16(A1[1], Bcur, bbv[1], 0, 0, 0);
        f32x4 a2 = __builtin_amdgcn_mfma_f32_16x16x32_bf16(A1[2], Bcur, bbv[2], 0, 0, 0);
        f32x4 a3 = __builtin_amdgcn_mfma_f32_16x16x32_bf16(A1[3], Bcur, bbv[3], 0, 0, 0);

        // relu (fmaxf: also NaN-squashing) + bf16 pack: result IS the layer-2
        // B fragment (tau-permuted w2)
        U ba, bb;
        ba.u[0] = cvtpk(fmaxf(a0[0], 0.f), fmaxf(a0[1], 0.f));
        ba.u[1] = cvtpk(fmaxf(a0[2], 0.f), fmaxf(a0[3], 0.f));
        ba.u[2] = cvtpk(fmaxf(a1[0], 0.f), fmaxf(a1[1], 0.f));
        ba.u[3] = cvtpk(fmaxf(a1[2], 0.f), fmaxf(a1[3], 0.f));
        bb.u[0] = cvtpk(fmaxf(a2[0], 0.f), fmaxf(a2[1], 0.f));
        bb.u[1] = cvtpk(fmaxf(a2[2], 0.f), fmaxf(a2[3], 0.f));
        bb.u[2] = cvtpk(fmaxf(a3[0], 0.f), fmaxf(a3[1], 0.f));
        bb.u[3] = cvtpk(fmaxf(a3[2], 0.f), fmaxf(a3[3], 0.f));

        f32x4 o = __builtin_amdgcn_mfma_f32_16x16x32_bf16(A2[0], ba.s, b2f, 0, 0, 0);
        o = __builtin_amdgcn_mfma_f32_16x16x32_bf16(A2[1], bb.s, o, 0, 0, 0);

        if (q < 2) {   // store d (clamped at 0; negatives never beat zeros baseline)
            uint2 ov;
            ov.x = cvtpk(fmaxf(o[0], 0.f), fmaxf(o[1], 0.f));
            ov.y = cvtpk(fmaxf(o[2], 0.f), fmaxf(o[3], 0.f));
            *(uint2*)(dst + (size_t)u * 2048 + j * 128) = ov;
        }
        Bcur = Bnext;
    }
}

// ---------------- gather-max per dest column -> d_out [f][r][c] directly ------
// grid (CDIM/GC, 2); 1024-thread block = 16 waves; wave w owns column c0+w for
// a 128-row half: rows rbase (acc A) and rbase+64 (acc B). Per entry the wave
// reads 2KB CONTIGUOUS from the tile (two back-to-back 1KB wave reads) --
// longer sequential runs per random tile touch vs R11's 1KB granularity.
__global__ __launch_bounds__(1024)
void gather_max_t(const unsigned short* __restrict__ dbuf, const int* __restrict__ mergecnt,
                  const int* __restrict__ mergelist, float* __restrict__ out) {
    __shared__ unsigned int ldsP[4][64][20];   // [f/2][rloc][c] packed bf16 pairs
    __shared__ int mlist[GC][MAXL];
    int t = threadIdx.x;
    int w = t >> 6, lane = t & 63;
    int c0 = blockIdx.x * GC;
    int c  = c0 + w;

    int n = mergecnt[c];
    n = n < 0 ? 0 : (n > MAXL ? MAXL : n);        // uniform across the wave
    if (lane < n) {
        int idx = mergelist[(size_t)c * MAXL + lane];
        idx = idx < 0 ? 0 : (idx >= NSETS * MDIM ? NSETS * MDIM - 1 : idx);
        mlist[w][lane] = idx;
    }
    __syncthreads();

    int rbase = blockIdx.y * 128 + lane;
    uint4 accA = make_uint4(0u, 0u, 0u, 0u);
    uint4 accB = make_uint4(0u, 0u, 0u, 0u);
    if (n > 0) {
        const unsigned short* bp = dbuf + ((size_t)mlist[w][0] * RDIM + rbase) * 8;
        uint4 pa = *(const uint4*)(bp);
        uint4 pb = *(const uint4*)(bp + 64 * 8);
        for (int e = 1; e < n; e++) {
            const unsigned short* bq = dbuf + ((size_t)mlist[w][e] * RDIM + rbase) * 8;
            uint4 qa = *(const uint4*)(bq);
            uint4 qb = *(const uint4*)(bq + 64 * 8);
            accA.x = pkmaxu(accA.x, pa.x); accA.y = pkmaxu(accA.y, pa.y);
            accA.z = pkmaxu(accA.z, pa.z); accA.w = pkmaxu(accA.w, pa.w);
            accB.x = pkmaxu(accB.x, pb.x); accB.y = pkmaxu(accB.y, pb.y);
            accB.z = pkmaxu(accB.z, pb.z); accB.w = pkmaxu(accB.w, pb.w);
            pa = qa; pb = qb;
        }
        accA.x = pkmaxu(accA.x, pa.x); accA.y = pkmaxu(accA.y, pa.y);
        accA.z = pkmaxu(accA.z, pa.z); accA.w = pkmaxu(accA.w, pa.w);
        accB.x = pkmaxu(accB.x, pb.x); accB.y = pkmaxu(accB.y, pb.y);
        accB.z = pkmaxu(accB.z, pb.z); accB.w = pkmaxu(accB.w, pb.w);
    }

    // two transpose/write phases (rows rbase.., then rbase+64..)
#pragma unroll
    for (int p = 0; p < 2; p++) {
        if (p) __syncthreads();             // prior read pass done before refill
        uint4 a = p ? accB : accA;
        ldsP[0][lane][w] = a.x;
        ldsP[1][lane][w] = a.y;
        ldsP[2][lane][w] = a.z;
        ldsP[3][lane][w] = a.w;
        __syncthreads();

        // one (f-pair, row, c-quad) per thread: 1024 = 4 * 64 * 4.
        // fmaxf(x,0) is identity on legit values (>=0), squashes NaN/neg.
        int f2 = t >> 8, rl = (t >> 2) & 63, cq = t & 3;
        uint4 v = *(const uint4*)&ldsP[f2][rl][cq * 4];
        float4 lo, hi;
        lo.x = fmaxf(__uint_as_float(v.x << 16), 0.f);
        hi.x = fmaxf(__uint_as_float(v.x & 0xffff0000u), 0.f);
        lo.y = fmaxf(__uint_as_float(v.y << 16), 0.f);
        hi.y = fmaxf(__uint_as_float(v.y & 0xffff0000u), 0.f);
        lo.z = fmaxf(__uint_as_float(v.z << 16), 0.f);
        hi.z = fmaxf(__uint_as_float(v.z & 0xffff0000u), 0.f);
        lo.w = fmaxf(__uint_as_float(v.w << 16), 0.f);
        hi.w = fmaxf(__uint_as_float(v.w & 0xffff0000u), 0.f);
        size_t rowoff = (size_t)blockIdx.y * 128 + p * 64 + rl;
        *(float4*)&out[((size_t)(2 * f2) * RDIM + rowoff) * CDIM + c0 + cq * 4] = lo;
        *(float4*)&out[((size_t)(2 * f2 + 1) * RDIM + rowoff) * CDIM + c0 + cq * 4] = hi;
    }
}

extern "C" void kernel_launch(void* const* d_in, const int* in_sizes, int n_in,
                              void* d_out, int out_size, void* d_ws, size_t ws_size,
                              hipStream_t stream) {
    const float* input = (const float*)d_in[0];
    const float* w1    = (const float*)d_in[1];
    const float* b1    = (const float*)d_in[2];
    const float* w2    = (const float*)d_in[3];
    const float* b2    = (const float*)d_in[4];
    const int*   ind0  = (const int*)d_in[5];
    const int*   ind1  = (const int*)d_in[6];
    const int*   ind2  = (const int*)d_in[7];
    const int*   mix   = (const int*)d_in[8];

    const size_t MiB = 1ull << 20;
    char* ws = (char*)d_ws;
    unsigned short* inT2 = (unsigned short*)ws;                    // 16 MiB
    unsigned short* dbuf = (unsigned short*)(ws + 16 * MiB);       // 48 MiB
    char* tail = ws + 64 * MiB;
    int* inv       = (int*)tail;                                   // 144 KiB
    int* mergecnt  = (int*)(tail + 147456);                        // 16 KiB
    int* mergelist = (int*)(tail + 147456 + 16384);                // 1 MiB
    unsigned short* w1bf = (unsigned short*)(tail + 147456 + 16384 + (size_t)CDIM * MAXL * 4);
    unsigned short* w2bf = w1bf + 64 * 32;

    prep_in<<<dim3(CDIM / 32, RDIM / 32), 256, 0, stream>>>(input, inT2);
    build_inv<<<dim3(NIND / 256, 9), 256, 0, stream>>>(ind0, ind1, ind2, w1, w2,
                                                       inv, mergecnt, w1bf, w2bf);
    build_buckets<<<dim3(MDIM / 256, 9), 256, 0, stream>>>(ind0, ind1, ind2, mix,
                                                           mergecnt, mergelist);
    mlp_store<<<NSETS * 2 * (MDIM / MPW) / 4, 256, 0, stream>>>(inT2, w1bf, w2bf, b1, b2,
                                                                ind0, ind1, ind2, mix, inv, dbuf);
    gather_max_t<<<dim3(CDIM / GC, 2), 1024, 0, stream>>>(dbuf, mergecnt, mergelist,
                                                          (float*)d_out);
}

// Round 14
// 85.814 us; speedup vs baseline: 2.7942x; 1.0031x over previous
//
#include <hip/hip_runtime.h>
#include <cstdint>

#define F_IN   8
#define HID    64
#define F_OUTD 8
#define RDIM   256
#define CDIM   4096
#define NSETS  3
#define NIND   4096
#define MDIM   4096
#define MAXL   64
#define GC     16
#define MPW    4

using short8 = __attribute__((ext_vector_type(8))) short;
using f32x4  = __attribute__((ext_vector_type(4))) float;

// hardware packed f32->bf16 (RNE), low word = a
__device__ inline unsigned int cvtpk(float a, float b) {
    unsigned int r;
    asm("v_cvt_pk_bf16_f32 %0, %1, %2" : "=v"(r) : "v"(a), "v"(b));
    return r;
}
// packed unsigned 16-bit max (== bf16 max for nonnegative values)
__device__ inline unsigned int pkmaxu(unsigned int a, unsigned int b) {
    unsigned int r;
    asm("v_pk_max_u16 %0, %1, %2" : "=v"(r) : "v"(a), "v"(b));
    return r;
}

// ---------------- input prep: in [F][R][C] f32 -> inT2 [C][R][F] bf16 ----------
__global__ __launch_bounds__(256)
void prep_in(const float* __restrict__ in, unsigned short* __restrict__ out) {
    const int PADH = 264;                       // halfs per c-row (528B)
    __shared__ unsigned short tile[32 * PADH];
    int c0 = blockIdx.x * 32, r0 = blockIdx.y * 32;
    int t = threadIdx.x;
    int tx = t & 31, ty = t >> 5;
#pragma unroll
    for (int f = 0; f < 8; f += 2)
#pragma unroll
        for (int rr = 0; rr < 4; rr++) {
            int r = ty + rr * 8;
            float v0 = in[((size_t)f * RDIM + (r0 + r)) * CDIM + c0 + tx];
            float v1 = in[((size_t)(f + 1) * RDIM + (r0 + r)) * CDIM + c0 + tx];
            *(unsigned int*)&tile[tx * PADH + r * 8 + f] = cvtpk(v0, v1);
        }
    __syncthreads();
    int r = t & 31, cl = t >> 5;
#pragma unroll
    for (int cc = 0; cc < 4; cc++) {
        int c = cc * 8 + cl;
        uint4 v = *(const uint4*)&tile[c * PADH + r * 8];
        *(uint4*)(out + (((size_t)(c0 + c) * RDIM) + (r0 + r)) * 8) = v;
    }
}

// ---------------- setup: inverse perms + mergecnt zero + weight prep ----------
// inv[si][c0]=k s.t. ind_i[s][k][0]==c0; block (0,0) converts weights to bf16.
// BIAS-AS-FEATURE: w1bf column k=24 holds b1[j]; the MLP feeds a constant
// B-fragment {1,0,...} for the q==3 lane group, so layer-1 needs no bias
// C-operand (16 fewer invariant VGPRs -> full fragment residency under the
// 64-VGPR occupancy budget). w2's columns are permuted by tau so layer-1's
// packed relu output (D-fragment order) is directly the layer-2 B-fragment:
//   tau(32*hi + 8*q + e) = 32*hi + 16*(e>>2) + 4*q + (e&3)
__global__ void build_inv(const int* __restrict__ ind0, const int* __restrict__ ind1,
                          const int* __restrict__ ind2,
                          const float* __restrict__ w1, const float* __restrict__ b1,
                          const float* __restrict__ w2,
                          int* __restrict__ inv, int* __restrict__ mergecnt,
                          unsigned short* __restrict__ w1bf, unsigned short* __restrict__ w2bf) {
    int k  = blockIdx.x * 256 + threadIdx.x;
    int si = blockIdx.y;
    int s_ = si / 3, i_ = si % 3;
    const int* ind = (i_ == 0 ? ind0 : (i_ == 1 ? ind1 : ind2)) + (size_t)s_ * NIND * 2;
    int c0 = ind[2 * k];
    inv[(size_t)si * NIND + c0] = k;
    if (si == 0) mergecnt[k] = 0;
    if (blockIdx.x == 0 && blockIdx.y == 0) {
        int t = threadIdx.x;
        for (int i = t; i < 64 * 32; i += 256) {
            int j = i >> 5, kk = i & 31;
            float v = (kk < 24) ? w1[j * 24 + kk] : (kk == 24 ? b1[j] : 0.f);
            w1bf[i] = (unsigned short)(cvtpk(v, 0.f) & 0xffff);
        }
        for (int i = t; i < 16 * 64; i += 256) {
            int f = i >> 6, kg = i & 63;
            int hi = kg >> 5, q = (kg >> 3) & 3, e = kg & 7;
            int j = (hi << 5) + ((e >> 2) << 4) + (q << 2) + (e & 3);   // tau
            w2bf[i] = (f < 8) ? (unsigned short)(cvtpk(w2[f * 64 + j], 0.f) & 0xffff) : 0;
        }
    }
}

// ---------------- bucket-invert the scatter into ONE merged list per column --
// mergelist[c][slot] = s*MDIM + m  (the d-tile index contributing to column c)
__global__ void build_buckets(const int* __restrict__ ind0, const int* __restrict__ ind1,
                              const int* __restrict__ ind2, const int* __restrict__ mix,
                              int* __restrict__ mergecnt, int* __restrict__ mergelist) {
    int m  = blockIdx.x * 256 + threadIdx.x;
    int si = blockIdx.y;
    int s_ = si / 3, i_ = si % 3;
    const int* ind = (i_ == 0 ? ind0 : (i_ == 1 ? ind1 : ind2)) + (size_t)s_ * NIND * 2;
    int mi = mix[(size_t)si * MDIM + m];
    int c  = ind[2 * mi + 1];
    int slot = atomicAdd(&mergecnt[c], 1);
    if (slot < MAXL) mergelist[(size_t)c * MAXL + slot] = s_ * MDIM + m;
}

// ---------------- MFMA MLP -> dense d[s*M+m][r][f] bf16 (clamped at 0) -----
// One wave per (s, half-of-r, group of MPW m). Fully in-register; w2 columns
// pre-permuted by tau so layer-1's packed relu output IS the layer-2 B frag.
// Layer-1 bias rides in w1bf col 24 against a constant {1,0,..} B-fragment
// for q==3 (no load); layer-1 C-operand is a single reusable zero vector.
__global__ __launch_bounds__(256, 2)
void mlp_store(const unsigned short* __restrict__ inT2,
               const unsigned short* __restrict__ w1bf,
               const unsigned short* __restrict__ w2bf,
               const float* __restrict__ b2,
               const int* __restrict__ ind0, const int* __restrict__ ind1,
               const int* __restrict__ ind2, const int* __restrict__ mix,
               const int* __restrict__ inv,
               unsigned short* __restrict__ dbuf) {
    int t    = threadIdx.x;
    int wave = t >> 6, lane = t & 63;
    int lo = lane & 15, q = lane >> 4;

    int wid  = blockIdx.x * 4 + wave;    // 0..6143
    int mgrp = wid & 1023;
    int half = (wid >> 10) & 1;
    int s_   = wid >> 11;
    int m0   = mgrp * MPW;

    short8 A1[4], A2[2];
#pragma unroll
    for (int tt = 0; tt < 4; tt++)
        A1[tt] = *(const short8*)(w1bf + ((16 * tt + lo) << 5) + (q << 3));
#pragma unroll
    for (int kk = 0; kk < 2; kk++)
        A2[kk] = *(const short8*)(w2bf + (lo << 6) + (kk << 5) + (q << 3));

    f32x4 zeroC = {0.f, 0.f, 0.f, 0.f};
    f32x4 b2f;
#pragma unroll
    for (int rg = 0; rg < 4; rg++) {
        int f = 4 * q + rg;
        b2f[rg] = (f < 8) ? b2[f] : 0.f;
    }

    // batched index chase: 3 rounds of MPW independent loads
    int gq[MPW] = {0, 0, 0, 0};
    if (q < 3) {
        int si = s_ * 3 + q;
        const int* indq = (q == 0 ? ind0 : (q == 1 ? ind1 : ind2)) + (size_t)s_ * NIND * 2;
        int mi[MPW], kk[MPW];
#pragma unroll
        for (int u = 0; u < MPW; u++) mi[u] = mix[(size_t)si * MDIM + m0 + u];
#pragma unroll
        for (int u = 0; u < MPW; u++) kk[u] = inv[(size_t)si * NIND + mi[u]];
#pragma unroll
        for (int u = 0; u < MPW; u++) gq[u] = indq[2 * kk[u] + 1];
    }
    const unsigned short* srcs[MPW];
#pragma unroll
    for (int u = 0; u < MPW; u++)
        srcs[u] = inT2 + ((size_t)gq[u] * RDIM + half * 128 + lo) * 8;

    unsigned short* dst = dbuf + (size_t)(s_ * MDIM + m0) * 2048 + half * 1024 + lo * 8 + q * 4;

    union U { unsigned int u[4]; short8 s; };
    // q==3: constant bias-feature fragment {1.0bf16, 0 x7}
    const short8 one8 = {(short)0x3F80, 0, 0, 0, 0, 0, 0, 0};

    short8 Bcur = one8;
    if (q < 3) Bcur = *(const short8*)srcs[0];
#pragma unroll
    for (int it = 0; it < MPW * 8; it++) {
        const int u = it >> 3, j = it & 7;
        short8 Bnext = Bcur;
        if (it < MPW * 8 - 1 && q < 3)
            Bnext = *(const short8*)(srcs[(it + 1) >> 3] + ((it + 1) & 7) * 128);

        f32x4 a0 = __builtin_amdgcn_mfma_f32_16x16x32_bf16(A1[0], Bcur, zeroC, 0, 0, 0);
        f32x4 a1 = __builtin_amdgcn_mfma_f32_16x16x32_bf16(A1[1], Bcur, zeroC, 0, 0, 0);
        f32x4 a2 = __builtin_amdgcn_mfma_f32_16x16x32_bf16(A1[2], Bcur, zeroC, 0, 0, 0);
        f32x4 a3 = __builtin_amdgcn_mfma_f32_16x16x32_bf16(A1[3], Bcur, zeroC, 0, 0, 0);

        // relu (fmaxf: also NaN-squashing) + bf16 pack: result IS the layer-2
        // B fragment (tau-permuted w2)
        U ba, bb;
        ba.u[0] = cvtpk(fmaxf(a0[0], 0.f), fmaxf(a0[1], 0.f));
        ba.u[1] = cvtpk(fmaxf(a0[2], 0.f), fmaxf(a0[3], 0.f));
        ba.u[2] = cvtpk(fmaxf(a1[0], 0.f), fmaxf(a1[1], 0.f));
        ba.u[3] = cvtpk(fmaxf(a1[2], 0.f), fmaxf(a1[3], 0.f));
        bb.u[0] = cvtpk(fmaxf(a2[0], 0.f), fmaxf(a2[1], 0.f));
        bb.u[1] = cvtpk(fmaxf(a2[2], 0.f), fmaxf(a2[3], 0.f));
        bb.u[2] = cvtpk(fmaxf(a3[0], 0.f), fmaxf(a3[1], 0.f));
        bb.u[3] = cvtpk(fmaxf(a3[2], 0.f), fmaxf(a3[3], 0.f));

        f32x4 o = __builtin_amdgcn_mfma_f32_16x16x32_bf16(A2[0], ba.s, b2f, 0, 0, 0);
        o = __builtin_amdgcn_mfma_f32_16x16x32_bf16(A2[1], bb.s, o, 0, 0, 0);

        if (q < 2) {   // store d (clamped at 0; negatives never beat zeros baseline)
            uint2 ov;
            ov.x = cvtpk(fmaxf(o[0], 0.f), fmaxf(o[1], 0.f));
            ov.y = cvtpk(fmaxf(o[2], 0.f), fmaxf(o[3], 0.f));
            *(uint2*)(dst + (size_t)u * 2048 + j * 128) = ov;
        }
        Bcur = Bnext;
    }
}

// ---------------- gather-max per dest column -> d_out [f][r][c] directly ------
// grid (CDIM/GC, 2); 1024-thread block = 16 waves; wave w owns column c0+w for
// a 128-row half: rows rbase (acc A) and rbase+64 (acc B). Per entry the wave
// reads 2KB contiguous (two back-to-back 1KB wave reads).
__global__ __launch_bounds__(1024)
void gather_max_t(const unsigned short* __restrict__ dbuf, const int* __restrict__ mergecnt,
                  const int* __restrict__ mergelist, float* __restrict__ out) {
    __shared__ unsigned int ldsP[4][64][20];   // [f/2][rloc][c] packed bf16 pairs
    __shared__ int mlist[GC][MAXL];
    int t = threadIdx.x;
    int w = t >> 6, lane = t & 63;
    int c0 = blockIdx.x * GC;
    int c  = c0 + w;

    int n = mergecnt[c];
    n = n < 0 ? 0 : (n > MAXL ? MAXL : n);        // uniform across the wave
    if (lane < n) {
        int idx = mergelist[(size_t)c * MAXL + lane];
        idx = idx < 0 ? 0 : (idx >= NSETS * MDIM ? NSETS * MDIM - 1 : idx);
        mlist[w][lane] = idx;
    }
    __syncthreads();

    int rbase = blockIdx.y * 128 + lane;
    uint4 accA = make_uint4(0u, 0u, 0u, 0u);
    uint4 accB = make_uint4(0u, 0u, 0u, 0u);
    if (n > 0) {
        const unsigned short* bp = dbuf + ((size_t)mlist[w][0] * RDIM + rbase) * 8;
        uint4 pa = *(const uint4*)(bp);
        uint4 pb = *(const uint4*)(bp + 64 * 8);
        for (int e = 1; e < n; e++) {
            const unsigned short* bq = dbuf + ((size_t)mlist[w][e] * RDIM + rbase) * 8;
            uint4 qa = *(const uint4*)(bq);
            uint4 qb = *(const uint4*)(bq + 64 * 8);
            accA.x = pkmaxu(accA.x, pa.x); accA.y = pkmaxu(accA.y, pa.y);
            accA.z = pkmaxu(accA.z, pa.z); accA.w = pkmaxu(accA.w, pa.w);
            accB.x = pkmaxu(accB.x, pb.x); accB.y = pkmaxu(accB.y, pb.y);
            accB.z = pkmaxu(accB.z, pb.z); accB.w = pkmaxu(accB.w, pb.w);
            pa = qa; pb = qb;
        }
        accA.x = pkmaxu(accA.x, pa.x); accA.y = pkmaxu(accA.y, pa.y);
        accA.z = pkmaxu(accA.z, pa.z); accA.w = pkmaxu(accA.w, pa.w);
        accB.x = pkmaxu(accB.x, pb.x); accB.y = pkmaxu(accB.y, pb.y);
        accB.z = pkmaxu(accB.z, pb.z); accB.w = pkmaxu(accB.w, pb.w);
    }

    // two transpose/write phases (rows rbase.., then rbase+64..)
#pragma unroll
    for (int p = 0; p < 2; p++) {
        if (p) __syncthreads();             // prior read pass done before refill
        uint4 a = p ? accB : accA;
        ldsP[0][lane][w] = a.x;
        ldsP[1][lane][w] = a.y;
        ldsP[2][lane][w] = a.z;
        ldsP[3][lane][w] = a.w;
        __syncthreads();

        // one (f-pair, row, c-quad) per thread: 1024 = 4 * 64 * 4.
        // fmaxf(x,0) is identity on legit values (>=0), squashes NaN/neg.
        int f2 = t >> 8, rl = (t >> 2) & 63, cq = t & 3;
        uint4 v = *(const uint4*)&ldsP[f2][rl][cq * 4];
        float4 lo, hi;
        lo.x = fmaxf(__uint_as_float(v.x << 16), 0.f);
        hi.x = fmaxf(__uint_as_float(v.x & 0xffff0000u), 0.f);
        lo.y = fmaxf(__uint_as_float(v.y << 16), 0.f);
        hi.y = fmaxf(__uint_as_float(v.y & 0xffff0000u), 0.f);
        lo.z = fmaxf(__uint_as_float(v.z << 16), 0.f);
        hi.z = fmaxf(__uint_as_float(v.z & 0xffff0000u), 0.f);
        lo.w = fmaxf(__uint_as_float(v.w << 16), 0.f);
        hi.w = fmaxf(__uint_as_float(v.w & 0xffff0000u), 0.f);
        size_t rowoff = (size_t)blockIdx.y * 128 + p * 64 + rl;
        *(float4*)&out[((size_t)(2 * f2) * RDIM + rowoff) * CDIM + c0 + cq * 4] = lo;
        *(float4*)&out[((size_t)(2 * f2 + 1) * RDIM + rowoff) * CDIM + c0 + cq * 4] = hi;
    }
}

extern "C" void kernel_launch(void* const* d_in, const int* in_sizes, int n_in,
                              void* d_out, int out_size, void* d_ws, size_t ws_size,
                              hipStream_t stream) {
    const float* input = (const float*)d_in[0];
    const float* w1    = (const float*)d_in[1];
    const float* b1    = (const float*)d_in[2];
    const float* w2    = (const float*)d_in[3];
    const float* b2    = (const float*)d_in[4];
    const int*   ind0  = (const int*)d_in[5];
    const int*   ind1  = (const int*)d_in[6];
    const int*   ind2  = (const int*)d_in[7];
    const int*   mix   = (const int*)d_in[8];

    const size_t MiB = 1ull << 20;
    char* ws = (char*)d_ws;
    unsigned short* inT2 = (unsigned short*)ws;                    // 16 MiB
    unsigned short* dbuf = (unsigned short*)(ws + 16 * MiB);       // 48 MiB
    char* tail = ws + 64 * MiB;
    int* inv       = (int*)tail;                                   // 144 KiB
    int* mergecnt  = (int*)(tail + 147456);                        // 16 KiB
    int* mergelist = (int*)(tail + 147456 + 16384);                // 1 MiB
    unsigned short* w1bf = (unsigned short*)(tail + 147456 + 16384 + (size_t)CDIM * MAXL * 4);
    unsigned short* w2bf = w1bf + 64 * 32;

    prep_in<<<dim3(CDIM / 32, RDIM / 32), 256, 0, stream>>>(input, inT2);
    build_inv<<<dim3(NIND / 256, 9), 256, 0, stream>>>(ind0, ind1, ind2, w1, b1, w2,
                                                       inv, mergecnt, w1bf, w2bf);
    build_buckets<<<dim3(MDIM / 256, 9), 256, 0, stream>>>(ind0, ind1, ind2, mix,
                                                           mergecnt, mergelist);
    mlp_store<<<NSETS * 2 * (MDIM / MPW) / 4, 256, 0, stream>>>(inT2, w1bf, w2bf, b2,
                                                                ind0, ind1, ind2, mix, inv, dbuf);
    gather_max_t<<<dim3(CDIM / GC, 2), 1024, 0, stream>>>(dbuf, mergecnt, mergelist,
                                                          (float*)d_out);
}

// Round 15
// 84.314 us; speedup vs baseline: 2.8439x; 1.0178x over previous
//
#include <hip/hip_runtime.h>
#include <cstdint>

#define F_IN   8
#define HID    64
#define F_OUTD 8
#define RDIM   256
#define CDIM   4096
#define NSETS  3
#define NIND   4096
#define MDIM   4096
#define MAXL   64
#define GC     16
#define MPW    4
#define PREPB  1024      // prep_in blocks inside setup kernel
#define MLPB   1536      // mlp blocks inside mlp+buckets kernel

using short8 = __attribute__((ext_vector_type(8))) short;
using f32x4  = __attribute__((ext_vector_type(4))) float;

// hardware packed f32->bf16 (RNE), low word = a
__device__ inline unsigned int cvtpk(float a, float b) {
    unsigned int r;
    asm("v_cvt_pk_bf16_f32 %0, %1, %2" : "=v"(r) : "v"(a), "v"(b));
    return r;
}
// packed unsigned 16-bit max (== bf16 max for nonnegative values)
__device__ inline unsigned int pkmaxu(unsigned int a, unsigned int b) {
    unsigned int r;
    asm("v_pk_max_u16 %0, %1, %2" : "=v"(r) : "v"(a), "v"(b));
    return r;
}

// ---------------- fused setup: prep_in + inverse perms + weight prep ----------
// blocks [0,PREPB): in [F][R][C] f32 -> inT2 [C][R][F] bf16 (tiled transpose).
// blocks [PREPB, PREPB+144): inv[si][c0]=k (si = b2/16); block PREPB also
// converts weights. BIAS-AS-FEATURE: w1bf col 24 = b1. w2 columns permuted by
// tau so layer-1's packed relu output (D-frag order) IS the layer-2 B-frag:
//   tau(32*hi + 8*q + e) = 32*hi + 16*(e>>2) + 4*q + (e&3)
// All parts have disjoint write sets and no intra-kernel readers -> race-free.
__global__ __launch_bounds__(256)
void setup1(const float* __restrict__ in, unsigned short* __restrict__ inT2,
            const int* __restrict__ ind0, const int* __restrict__ ind1,
            const int* __restrict__ ind2,
            const float* __restrict__ w1, const float* __restrict__ b1,
            const float* __restrict__ w2,
            int* __restrict__ inv,
            unsigned short* __restrict__ w1bf, unsigned short* __restrict__ w2bf) {
    const int PADH = 264;                       // halfs per c-row (528B)
    __shared__ unsigned short tile[32 * PADH];
    int b = blockIdx.x;
    int t = threadIdx.x;
    if (b < PREPB) {
        int c0 = (b & 127) * 32, r0 = (b >> 7) * 32;
        int tx = t & 31, ty = t >> 5;
#pragma unroll
        for (int f = 0; f < 8; f += 2)
#pragma unroll
            for (int rr = 0; rr < 4; rr++) {
                int r = ty + rr * 8;
                float v0 = in[((size_t)f * RDIM + (r0 + r)) * CDIM + c0 + tx];
                float v1 = in[((size_t)(f + 1) * RDIM + (r0 + r)) * CDIM + c0 + tx];
                *(unsigned int*)&tile[tx * PADH + r * 8 + f] = cvtpk(v0, v1);
            }
        __syncthreads();
        int r = t & 31, cl = t >> 5;
#pragma unroll
        for (int cc = 0; cc < 4; cc++) {
            int c = cc * 8 + cl;
            uint4 v = *(const uint4*)&tile[c * PADH + r * 8];
            *(uint4*)(inT2 + (((size_t)(c0 + c) * RDIM) + (r0 + r)) * 8) = v;
        }
    } else {
        int b2 = b - PREPB;                     // 0..143
        int si = b2 >> 4, kb = b2 & 15;
        int k  = kb * 256 + t;
        int s_ = si / 3, i_ = si % 3;
        const int* ind = (i_ == 0 ? ind0 : (i_ == 1 ? ind1 : ind2)) + (size_t)s_ * NIND * 2;
        int c0 = ind[2 * k];
        inv[(size_t)si * NIND + c0] = k;
        if (b2 == 0) {
            for (int i = t; i < 64 * 32; i += 256) {
                int j = i >> 5, kk = i & 31;
                float v = (kk < 24) ? w1[j * 24 + kk] : (kk == 24 ? b1[j] : 0.f);
                w1bf[i] = (unsigned short)(cvtpk(v, 0.f) & 0xffff);
            }
            for (int i = t; i < 16 * 64; i += 256) {
                int f = i >> 6, kg = i & 63;
                int hi = kg >> 5, q = (kg >> 3) & 3, e = kg & 7;
                int j = (hi << 5) + ((e >> 2) << 4) + (q << 2) + (e & 3);   // tau
                w2bf[i] = (f < 8) ? (unsigned short)(cvtpk(w2[f * 64 + j], 0.f) & 0xffff) : 0;
            }
        }
    }
}

// ---------------- MFMA MLP -> dense d, with build_buckets folded in ----------
// blocks [0,MLPB): one wave per (s, half-of-r, group of MPW m); fully
// in-register (tau-permuted w2, bias-as-feature with constant {1,0,..} B-frag
// for q==3). blocks [MLPB, MLPB+144): bucket-invert the scatter into one
// merged per-column list (mergelist[c][slot] = s*MDIM+m). Disjoint writes;
// gather (next launch) is the only reader of mergecnt/mergelist; max is
// order-independent so slot-order nondeterminism doesn't reach d_out.
__global__ __launch_bounds__(256, 2)
void mlp_store(const unsigned short* __restrict__ inT2,
               const unsigned short* __restrict__ w1bf,
               const unsigned short* __restrict__ w2bf,
               const float* __restrict__ b2,
               const int* __restrict__ ind0, const int* __restrict__ ind1,
               const int* __restrict__ ind2, const int* __restrict__ mix,
               const int* __restrict__ inv,
               unsigned short* __restrict__ dbuf,
               int* __restrict__ mergecnt, int* __restrict__ mergelist) {
    int t = threadIdx.x;
    if (blockIdx.x >= MLPB) {                  // ---- build_buckets part ----
        int b2_ = blockIdx.x - MLPB;           // 0..143
        int si = b2_ >> 4;
        int m  = (b2_ & 15) * 256 + t;
        int s_ = si / 3, i_ = si % 3;
        const int* ind = (i_ == 0 ? ind0 : (i_ == 1 ? ind1 : ind2)) + (size_t)s_ * NIND * 2;
        int mi = mix[(size_t)si * MDIM + m];
        int c  = ind[2 * mi + 1];
        int slot = atomicAdd(&mergecnt[c], 1);
        if (slot < MAXL) mergelist[(size_t)c * MAXL + slot] = s_ * MDIM + m;
        return;
    }

    int wave = t >> 6, lane = t & 63;
    int lo = lane & 15, q = lane >> 4;

    int wid  = blockIdx.x * 4 + wave;    // 0..6143
    int mgrp = wid & 1023;
    int half = (wid >> 10) & 1;
    int s_   = wid >> 11;
    int m0   = mgrp * MPW;

    short8 A1[4], A2[2];
#pragma unroll
    for (int tt = 0; tt < 4; tt++)
        A1[tt] = *(const short8*)(w1bf + ((16 * tt + lo) << 5) + (q << 3));
#pragma unroll
    for (int kk = 0; kk < 2; kk++)
        A2[kk] = *(const short8*)(w2bf + (lo << 6) + (kk << 5) + (q << 3));

    f32x4 zeroC = {0.f, 0.f, 0.f, 0.f};
    f32x4 b2f;
#pragma unroll
    for (int rg = 0; rg < 4; rg++) {
        int f = 4 * q + rg;
        b2f[rg] = (f < 8) ? b2[f] : 0.f;
    }

    // batched index chase: 3 rounds of MPW independent loads
    int gq[MPW] = {0, 0, 0, 0};
    if (q < 3) {
        int si = s_ * 3 + q;
        const int* indq = (q == 0 ? ind0 : (q == 1 ? ind1 : ind2)) + (size_t)s_ * NIND * 2;
        int mi[MPW], kk[MPW];
#pragma unroll
        for (int u = 0; u < MPW; u++) mi[u] = mix[(size_t)si * MDIM + m0 + u];
#pragma unroll
        for (int u = 0; u < MPW; u++) kk[u] = inv[(size_t)si * NIND + mi[u]];
#pragma unroll
        for (int u = 0; u < MPW; u++) gq[u] = indq[2 * kk[u] + 1];
    }
    const unsigned short* srcs[MPW];
#pragma unroll
    for (int u = 0; u < MPW; u++)
        srcs[u] = inT2 + ((size_t)gq[u] * RDIM + half * 128 + lo) * 8;

    unsigned short* dst = dbuf + (size_t)(s_ * MDIM + m0) * 2048 + half * 1024 + lo * 8 + q * 4;

    union U { unsigned int u[4]; short8 s; };
    // q==3: constant bias-feature fragment {1.0bf16, 0 x7}
    const short8 one8 = {(short)0x3F80, 0, 0, 0, 0, 0, 0, 0};

    short8 Bcur = one8;
    if (q < 3) Bcur = *(const short8*)srcs[0];
#pragma unroll
    for (int it = 0; it < MPW * 8; it++) {
        const int u = it >> 3, j = it & 7;
        short8 Bnext = Bcur;
        if (it < MPW * 8 - 1 && q < 3)
            Bnext = *(const short8*)(srcs[(it + 1) >> 3] + ((it + 1) & 7) * 128);

        f32x4 a0 = __builtin_amdgcn_mfma_f32_16x16x32_bf16(A1[0], Bcur, zeroC, 0, 0, 0);
        f32x4 a1 = __builtin_amdgcn_mfma_f32_16x16x32_bf16(A1[1], Bcur, zeroC, 0, 0, 0);
        f32x4 a2 = __builtin_amdgcn_mfma_f32_16x16x32_bf16(A1[2], Bcur, zeroC, 0, 0, 0);
        f32x4 a3 = __builtin_amdgcn_mfma_f32_16x16x32_bf16(A1[3], Bcur, zeroC, 0, 0, 0);

        // relu (fmaxf: also NaN-squashing) + bf16 pack: result IS the layer-2
        // B fragment (tau-permuted w2)
        U ba, bb;
        ba.u[0] = cvtpk(fmaxf(a0[0], 0.f), fmaxf(a0[1], 0.f));
        ba.u[1] = cvtpk(fmaxf(a0[2], 0.f), fmaxf(a0[3], 0.f));
        ba.u[2] = cvtpk(fmaxf(a1[0], 0.f), fmaxf(a1[1], 0.f));
        ba.u[3] = cvtpk(fmaxf(a1[2], 0.f), fmaxf(a1[3], 0.f));
        bb.u[0] = cvtpk(fmaxf(a2[0], 0.f), fmaxf(a2[1], 0.f));
        bb.u[1] = cvtpk(fmaxf(a2[2], 0.f), fmaxf(a2[3], 0.f));
        bb.u[2] = cvtpk(fmaxf(a3[0], 0.f), fmaxf(a3[1], 0.f));
        bb.u[3] = cvtpk(fmaxf(a3[2], 0.f), fmaxf(a3[3], 0.f));

        f32x4 o = __builtin_amdgcn_mfma_f32_16x16x32_bf16(A2[0], ba.s, b2f, 0, 0, 0);
        o = __builtin_amdgcn_mfma_f32_16x16x32_bf16(A2[1], bb.s, o, 0, 0, 0);

        if (q < 2) {   // store d (clamped at 0; negatives never beat zeros baseline)
            uint2 ov;
            ov.x = cvtpk(fmaxf(o[0], 0.f), fmaxf(o[1], 0.f));
            ov.y = cvtpk(fmaxf(o[2], 0.f), fmaxf(o[3], 0.f));
            *(uint2*)(dst + (size_t)u * 2048 + j * 128) = ov;
        }
        Bcur = Bnext;
    }
}

// ---------------- gather-max per dest column -> d_out [f][r][c] directly ------
// grid (CDIM/GC, 2); 1024-thread block = 16 waves; wave w owns column c0+w for
// a 128-row half: rows rbase (acc A) and rbase+64 (acc B). Per entry the wave
// reads 2KB contiguous (two back-to-back 1KB wave reads).
__global__ __launch_bounds__(1024)
void gather_max_t(const unsigned short* __restrict__ dbuf, const int* __restrict__ mergecnt,
                  const int* __restrict__ mergelist, float* __restrict__ out) {
    __shared__ unsigned int ldsP[4][64][20];   // [f/2][rloc][c] packed bf16 pairs
    __shared__ int mlist[GC][MAXL];
    int t = threadIdx.x;
    int w = t >> 6, lane = t & 63;
    int c0 = blockIdx.x * GC;
    int c  = c0 + w;

    int n = mergecnt[c];
    n = n < 0 ? 0 : (n > MAXL ? MAXL : n);        // uniform across the wave
    if (lane < n) {
        int idx = mergelist[(size_t)c * MAXL + lane];
        idx = idx < 0 ? 0 : (idx >= NSETS * MDIM ? NSETS * MDIM - 1 : idx);
        mlist[w][lane] = idx;
    }
    __syncthreads();

    int rbase = blockIdx.y * 128 + lane;
    uint4 accA = make_uint4(0u, 0u, 0u, 0u);
    uint4 accB = make_uint4(0u, 0u, 0u, 0u);
    if (n > 0) {
        const unsigned short* bp = dbuf + ((size_t)mlist[w][0] * RDIM + rbase) * 8;
        uint4 pa = *(const uint4*)(bp);
        uint4 pb = *(const uint4*)(bp + 64 * 8);
        for (int e = 1; e < n; e++) {
            const unsigned short* bq = dbuf + ((size_t)mlist[w][e] * RDIM + rbase) * 8;
            uint4 qa = *(const uint4*)(bq);
            uint4 qb = *(const uint4*)(bq + 64 * 8);
            accA.x = pkmaxu(accA.x, pa.x); accA.y = pkmaxu(accA.y, pa.y);
            accA.z = pkmaxu(accA.z, pa.z); accA.w = pkmaxu(accA.w, pa.w);
            accB.x = pkmaxu(accB.x, pb.x); accB.y = pkmaxu(accB.y, pb.y);
            accB.z = pkmaxu(accB.z, pb.z); accB.w = pkmaxu(accB.w, pb.w);
            pa = qa; pb = qb;
        }
        accA.x = pkmaxu(accA.x, pa.x); accA.y = pkmaxu(accA.y, pa.y);
        accA.z = pkmaxu(accA.z, pa.z); accA.w = pkmaxu(accA.w, pa.w);
        accB.x = pkmaxu(accB.x, pb.x); accB.y = pkmaxu(accB.y, pb.y);
        accB.z = pkmaxu(accB.z, pb.z); accB.w = pkmaxu(accB.w, pb.w);
    }

    // two transpose/write phases (rows rbase.., then rbase+64..)
#pragma unroll
    for (int p = 0; p < 2; p++) {
        if (p) __syncthreads();             // prior read pass done before refill
        uint4 a = p ? accB : accA;
        ldsP[0][lane][w] = a.x;
        ldsP[1][lane][w] = a.y;
        ldsP[2][lane][w] = a.z;
        ldsP[3][lane][w] = a.w;
        __syncthreads();

        // one (f-pair, row, c-quad) per thread: 1024 = 4 * 64 * 4.
        // fmaxf(x,0) is identity on legit values (>=0), squashes NaN/neg.
        int f2 = t >> 8, rl = (t >> 2) & 63, cq = t & 3;
        uint4 v = *(const uint4*)&ldsP[f2][rl][cq * 4];
        float4 lo, hi;
        lo.x = fmaxf(__uint_as_float(v.x << 16), 0.f);
        hi.x = fmaxf(__uint_as_float(v.x & 0xffff0000u), 0.f);
        lo.y = fmaxf(__uint_as_float(v.y << 16), 0.f);
        hi.y = fmaxf(__uint_as_float(v.y & 0xffff0000u), 0.f);
        lo.z = fmaxf(__uint_as_float(v.z << 16), 0.f);
        hi.z = fmaxf(__uint_as_float(v.z & 0xffff0000u), 0.f);
        lo.w = fmaxf(__uint_as_float(v.w << 16), 0.f);
        hi.w = fmaxf(__uint_as_float(v.w & 0xffff0000u), 0.f);
        size_t rowoff = (size_t)blockIdx.y * 128 + p * 64 + rl;
        *(float4*)&out[((size_t)(2 * f2) * RDIM + rowoff) * CDIM + c0 + cq * 4] = lo;
        *(float4*)&out[((size_t)(2 * f2 + 1) * RDIM + rowoff) * CDIM + c0 + cq * 4] = hi;
    }
}

extern "C" void kernel_launch(void* const* d_in, const int* in_sizes, int n_in,
                              void* d_out, int out_size, void* d_ws, size_t ws_size,
                              hipStream_t stream) {
    const float* input = (const float*)d_in[0];
    const float* w1    = (const float*)d_in[1];
    const float* b1    = (const float*)d_in[2];
    const float* w2    = (const float*)d_in[3];
    const float* b2    = (const float*)d_in[4];
    const int*   ind0  = (const int*)d_in[5];
    const int*   ind1  = (const int*)d_in[6];
    const int*   ind2  = (const int*)d_in[7];
    const int*   mix   = (const int*)d_in[8];

    const size_t MiB = 1ull << 20;
    char* ws = (char*)d_ws;
    unsigned short* inT2 = (unsigned short*)ws;                    // 16 MiB
    unsigned short* dbuf = (unsigned short*)(ws + 16 * MiB);       // 48 MiB
    char* tail = ws + 64 * MiB;
    int* inv       = (int*)tail;                                   // 144 KiB
    int* mergecnt  = (int*)(tail + 147456);                        // 16 KiB
    int* mergelist = (int*)(tail + 147456 + 16384);                // 1 MiB
    unsigned short* w1bf = (unsigned short*)(tail + 147456 + 16384 + (size_t)CDIM * MAXL * 4);
    unsigned short* w2bf = w1bf + 64 * 32;

    hipMemsetAsync(mergecnt, 0, CDIM * sizeof(int), stream);       // graph-capturable
    setup1<<<PREPB + 144, 256, 0, stream>>>(input, inT2, ind0, ind1, ind2,
                                            w1, b1, w2, inv, w1bf, w2bf);
    mlp_store<<<MLPB + 144, 256, 0, stream>>>(inT2, w1bf, w2bf, b2,
                                              ind0, ind1, ind2, mix, inv, dbuf,
                                              mergecnt, mergelist);
    gather_max_t<<<dim3(CDIM / GC, 2), 1024, 0, stream>>>(dbuf, mergecnt, mergelist,
                                                          (float*)d_out);
}